// Round 10
// baseline (309.448 us; speedup 1.0000x reference)
//
#include <hip/hip_runtime.h>
#include <hip/hip_bf16.h>
#include <math.h>

// Problem constants
#define BB   16
#define CI   16
#define CO   16
#define HH   384
#define WW   384
#define HW   (HH * WW)

// Padded pixel-major bf16 layout: XP[b][386][386][16ci], 32B per pixel
#define PW 386

// Conv tiling: 32 wide x 16 tall output tile
#define TSW 32
#define TSH 16
#define HSW 34
#define HSH 18
#define NPX (HSW * HSH)  // 612 staged pixels, 1224 16B-chunks

// prep LDS plane stride in dwords: 2 rows x 384 + 4 pad (16B-aligned, and
// (772 % 32) = 4 -> transpose reads hit all banks)
#define PSTR 772

typedef __bf16 bfx8 __attribute__((ext_vector_type(8)));
typedef float  f32x4 __attribute__((ext_vector_type(4)));

// RNE pack of two f32 -> bf16x2 in a uint32 (lo = a, hi = b)
__device__ __forceinline__ uint32_t pack_bf16(float a, float b) {
  uint32_t ua = __builtin_bit_cast(uint32_t, a);
  uint32_t ub = __builtin_bit_cast(uint32_t, b);
  ua = (ua + 0x7FFFu + ((ua >> 16) & 1u)) >> 16;
  ub = (ub + 0x7FFFu + ((ub >> 16) & 1u)) >> 16;
  return ua | (ub << 16);
}

__device__ __forceinline__ void gl_lds16(const void* g, void* l) {
  __builtin_amdgcn_global_load_lds(
      (const __attribute__((address_space(1))) uint32_t*)g,
      (__attribute__((address_space(3))) uint32_t*)l, 16, 0, 0);
}

// ===========================================================================
// FAST PATH
// ===========================================================================

// ---------------------------------------------------------------------------
// prep: x [B][CI][H][W] f32 -> XP padded [B][386][386][CI] bf16 + pool counts.
// Grid (192, B), 384 threads (6 waves). Block = 2-row strip.
// Stage: 48 x 1KB global_load_lds DMA ops (8/wave, deep vmcnt queue) into
// LDS [16 planes][772 dw]. Then transpose-read (conflict-free), pack, store.
// ---------------------------------------------------------------------------
__global__ __launch_bounds__(384) void prep_kernel(
    const float* __restrict__ x, uint4* __restrict__ XP,
    int* __restrict__ pooled) {
  const int b   = blockIdx.y;
  const int h0  = blockIdx.x * 2;
  const int tid = threadIdx.x;
  const int lane = tid & 63;
  const int wv   = tid >> 6;        // 0..5

  __shared__ __align__(16) uint32_t sxs[CI * PSTR];  // 49,408 B

  // --- stage 16 planes x 768 dwords (rows h0, h0+1) via DMA ---
  const float* xb = x + (size_t)b * CI * HW + (size_t)h0 * WW;
#pragma unroll
  for (int i = 0; i < 8; ++i) {
    const int j  = wv * 8 + i;      // 0..47, wave-uniform
    const int pl = j / 3;
    const int k  = j - pl * 3;      // 1KB chunk 0..2
    const float* src = xb + (size_t)pl * HW + k * 256 + lane * 4;
    gl_lds16(src, (char*)sxs + pl * (PSTR * 4) + k * 1024);
  }
  __syncthreads();  // drains vmcnt (global_load_lds) before LDS reads

  // --- transpose out of LDS: 2 pixels per thread (col=tid, rows h0/h0+1) ---
  int cnt[CI];
#pragma unroll
  for (int ci = 0; ci < CI; ++ci) cnt[ci] = 0;

#pragma unroll
  for (int half = 0; half < 2; ++half) {
    const int p = tid + half * 384;  // dword index within plane tile
    uint32_t pk[8];
#pragma unroll
    for (int i = 0; i < 8; ++i) {
      const float v0 = __builtin_bit_cast(float, sxs[(2 * i) * PSTR + p]);
      const float v1 = __builtin_bit_cast(float, sxs[(2 * i + 1) * PSTR + p]);
      cnt[2 * i]     += (v0 >= 0.f);
      cnt[2 * i + 1] += (v1 >= 0.f);
      pk[i] = pack_bf16(v0, v1);
    }
    uint4 lo, hi;
    lo.x = pk[0]; lo.y = pk[1]; lo.z = pk[2]; lo.w = pk[3];
    hi.x = pk[4]; hi.y = pk[5]; hi.z = pk[6]; hi.w = pk[7];
    uint4* dst =
        XP + (((size_t)b * PW + (h0 + half + 1)) * PW + (tid + 1)) * 2;
    dst[0] = lo;
    dst[1] = hi;
  }

  // --- pool reduce within aligned 32-lane groups (one (h,w)-bin each) ---
#pragma unroll
  for (int ci = 0; ci < CI; ++ci) {
#pragma unroll
    for (int s = 1; s < 32; s <<= 1)
      cnt[ci] += __shfl_xor(cnt[ci], s, 64);
  }
  if ((tid & 31) == 0) {
    const int bin = (h0 >> 7) * 3 + (tid >> 7);
#pragma unroll
    for (int ci = 0; ci < CI; ++ci)
      atomicAdd(&pooled[(b * CI + ci) * 9 + bin], cnt[ci]);
  }
}

// ---------------------------------------------------------------------------
// border: zero the padded frame of XP. Grid (B), 384 threads.
// ---------------------------------------------------------------------------
__global__ __launch_bounds__(384) void border_kernel(uint4* __restrict__ XP) {
  const int b = blockIdx.x;
  const int tid = threadIdx.x;
  const uint4 z = {0u, 0u, 0u, 0u};
  for (int j = tid; j < 1540; j += 384) {
    int pr, pc;
    if (j < 386)       { pr = 0;            pc = j; }
    else if (j < 772)  { pr = PW - 1;       pc = j - 386; }
    else if (j < 1156) { pr = j - 772 + 1;  pc = 0; }
    else               { pr = j - 1156 + 1; pc = PW - 1; }
    uint4* p = XP + (((size_t)b * PW + pr) * PW + pc) * 2;
    p[0] = z; p[1] = z;
  }
}

// ---------------------------------------------------------------------------
// att_finish_int: softmax+sigmoid. 1 block x 256 threads (1 per plane).
// ---------------------------------------------------------------------------
__global__ __launch_bounds__(256) void att_finish_int(
    const int* __restrict__ pooled, float* __restrict__ att) {
  const int plane = threadIdx.x;
  float v[9];
#pragma unroll
  for (int k = 0; k < 9; ++k)
    v[k] = (float)pooled[plane * 9 + k] * (1.f / 16384.f);
  float m = v[0];
#pragma unroll
  for (int k = 1; k < 9; ++k) m = fmaxf(m, v[k]);
  float e[9], s = 0.f;
#pragma unroll
  for (int k = 0; k < 9; ++k) { e[k] = expf(v[k] - m); s += e[k]; }
  const float inv = 1.f / s;
#pragma unroll
  for (int k = 0; k < 9; ++k) {
    const float a = 9.f * e[k] * inv - 1.f;
    att[plane * 9 + k] = 1.f + 1.f / (1.f + expf(-a));
  }
}

// ---------------------------------------------------------------------------
// conv_fast: bf16 MFMA implicit-GEMM conv, staging from XP via global_load_lds.
// y stores are nontemporal: y is never re-read during timing, keep L3 for x+XP.
// ---------------------------------------------------------------------------
__global__ __launch_bounds__(256) void conv_fast(
    const char* __restrict__ XPc, const float* __restrict__ Wt,
    const float* __restrict__ att, float* __restrict__ y) {
  const int b   = blockIdx.z;
  const int gx0 = blockIdx.x * TSW;
  const int gy0 = blockIdx.y * TSH;
  const int tid = threadIdx.x;

  __shared__ __align__(16) uint32_t sx[NPX * 8];   // 19,584 B
  __shared__ __align__(16) uint32_t sw[CO * 80];   //  5,120 B

  const int lane = tid & 63;
  const int wv   = tid >> 6;

  // --- stage x tile from XP: 1224 16B chunks, 20 wave-iterations total ---
  const char* XPb = XPc + (size_t)b * (PW * PW * 32);
#pragma unroll
  for (int i = wv; i < 20; i += 4) {
    const int chunk = i * 64 + lane;
    const int px  = chunk >> 1;
    const int hf  = chunk & 1;
    const int rr  = px / HSW;
    const int cc  = px - rr * HSW;
    const int swz = (cc >> 2) & 1;
    const char* src =
        XPb + (((size_t)(gy0 + rr) * PW + (gx0 + cc)) << 5) + ((hf ^ swz) << 4);
    if (chunk < 2 * NPX) gl_lds16(src, (char*)sx + i * 1024);
  }

  // --- modulated weights -> sw[cout][k/2] packed bf16 pairs, k = pos*16+ci ---
#pragma unroll
  for (int i = 0; i < 5; ++i) {
    const int idx  = tid + 256 * i;  // 0..1279
    const int cout = idx / 80;
    const int kp   = idx - cout * 80;
    const int k0 = 2 * kp, k1 = 2 * kp + 1;
    const int p0 = k0 >> 4, ci0 = k0 & 15;
    const int p1 = k1 >> 4, ci1 = k1 & 15;
    float v0 = 0.f, v1 = 0.f;
    if (p0 < 9) v0 = Wt[(cout * CI + ci0) * 9 + p0] * att[(b * CI + ci0) * 9 + p0];
    if (p1 < 9) v1 = Wt[(cout * CI + ci1) * 9 + p1] * att[(b * CI + ci1) * 9 + p1];
    sw[cout * 80 + kp] = pack_bf16(v0, v1);
  }
  __syncthreads();

  const int cpix = lane & 15;        // pixel col within group / A row (cout)
  const int h4   = lane >> 4;        // 0..3: A k-group; D row group
  const int hB   = h4 & 1;           // B ci-half
  const int pp   = lane >> 5;        // B pos parity

  // A fragments: Wmod[cout=cpix][k chunk q]
  bfx8 aw[5];
  const char* swb = (const char*)sw;
#pragma unroll
  for (int q = 0; q < 5; ++q)
    aw[q] = *(const bfx8*)(swb + cpix * 320 + q * 64 + h4 * 16);

  // B per-lane byte offsets into sx for each K-chunk
  int Lq[5];
#pragma unroll
  for (int q = 0; q < 5; ++q) {
    int p = 2 * q + pp;
    if (p > 8) p = 8;                // k>=144: weights are zero; clamp addr
    const int dy = p / 3, dx = p - 3 * dy;
    const int ccl = cpix + dx;
    const int swz = (ccl >> 2) & 1;
    Lq[q] = (dy * HSW + ccl) * 32 + 16 * (hB ^ swz);
  }

  const char* sxb = (const char*)sx;
  float* yb = y + ((size_t)b * CO + h4 * 4) * HW + (size_t)gy0 * WW + gx0 + cpix;

#pragma unroll 2
  for (int ri = 0; ri < 4; ++ri) {
    const int r = wv * 4 + ri;
    const int gbase = (r * HSW) * 32;
    f32x4 a0 = {0.f, 0.f, 0.f, 0.f};
    f32x4 a1 = {0.f, 0.f, 0.f, 0.f};
#pragma unroll
    for (int q = 0; q < 5; ++q) {
      const bfx8 b0 = *(const bfx8*)(sxb + gbase + Lq[q]);
      const bfx8 b1 = *(const bfx8*)(sxb + gbase + 512 + Lq[q]);  // c0 = 16
      a0 = __builtin_amdgcn_mfma_f32_16x16x32_bf16(aw[q], b0, a0, 0, 0, 0);
      a1 = __builtin_amdgcn_mfma_f32_16x16x32_bf16(aw[q], b1, a1, 0, 0, 0);
    }
    float* yr = yb + (size_t)r * WW;
#pragma unroll
    for (int j = 0; j < 4; ++j) {
      __builtin_nontemporal_store(a0[j], &yr[(size_t)j * HW]);
      __builtin_nontemporal_store(a1[j], &yr[(size_t)j * HW + 16]);
    }
  }
}

// ===========================================================================
// LEGACY FALLBACK (round-5 path) — used only if ws_size is too small
// ===========================================================================
__global__ __launch_bounds__(256) void pool_kernel(
    const float* __restrict__ x, float* __restrict__ pooled) {
  const int bx = blockIdx.x;
  const int plane = bx / 9;
  const int bin = bx - plane * 9;
  const int br = (bin / 3) * 128;
  const int bc4 = (bin % 3) * 32;
  const float4* xp = (const float4*)(x + (size_t)plane * HW);
  const int tid = threadIdx.x;
  int cnt = 0;
#pragma unroll
  for (int k = 0; k < 16; ++k) {
    const int idx = tid + k * 256;
    const int r = idx >> 5;
    const int c4 = idx & 31;
    const float4 v = xp[(size_t)(br + r) * (WW / 4) + bc4 + c4];
    cnt += (v.x >= 0.f) + (v.y >= 0.f) + (v.z >= 0.f) + (v.w >= 0.f);
  }
#pragma unroll
  for (int s = 32; s > 0; s >>= 1) cnt += __shfl_down(cnt, s);
  __shared__ int wsum[4];
  const int lane = tid & 63, wid = tid >> 6;
  if (lane == 0) wsum[wid] = cnt;
  __syncthreads();
  if (tid == 0)
    pooled[bx] = (float)(wsum[0] + wsum[1] + wsum[2] + wsum[3]) * (1.f / 16384.f);
}

__global__ __launch_bounds__(256) void att_finish(
    const float* __restrict__ pooled, float* __restrict__ att) {
  const int plane = threadIdx.x;
  float v[9];
#pragma unroll
  for (int k = 0; k < 9; ++k) v[k] = pooled[plane * 9 + k];
  float m = v[0];
#pragma unroll
  for (int k = 1; k < 9; ++k) m = fmaxf(m, v[k]);
  float e[9], s = 0.f;
#pragma unroll
  for (int k = 0; k < 9; ++k) { e[k] = expf(v[k] - m); s += e[k]; }
  const float inv = 1.f / s;
#pragma unroll
  for (int k = 0; k < 9; ++k) {
    const float a = 9.f * e[k] * inv - 1.f;
    att[plane * 9 + k] = 1.f + 1.f / (1.f + expf(-a));
  }
}

__global__ __launch_bounds__(256) void conv_legacy(
    const float* __restrict__ x, const float* __restrict__ Wt,
    const float* __restrict__ att, float* __restrict__ y) {
  const int b   = blockIdx.z;
  const int gx0 = blockIdx.x * TSW;
  const int gy0 = blockIdx.y * TSH;
  const int tid = threadIdx.x;
  __shared__ __align__(16) uint32_t sx[NPX * 8];
  __shared__ __align__(16) uint32_t sw[CO * 80];
  const float* xb = x + (size_t)b * CI * HW;
#pragma unroll
  for (int i = 0; i < 5; ++i) {
    const int idx  = tid + 256 * i;
    const int cout = idx / 80;
    const int kp   = idx - cout * 80;
    const int k0 = 2 * kp, k1 = 2 * kp + 1;
    const int p0 = k0 >> 4, ci0 = k0 & 15;
    const int p1 = k1 >> 4, ci1 = k1 & 15;
    float v0 = 0.f, v1 = 0.f;
    if (p0 < 9) v0 = Wt[(cout * CI + ci0) * 9 + p0] * att[(b * CI + ci0) * 9 + p0];
    if (p1 < 9) v1 = Wt[(cout * CI + ci1) * 9 + p1] * att[(b * CI + ci1) * 9 + p1];
    sw[cout * 80 + kp] = pack_bf16(v0, v1);
  }
#pragma unroll
  for (int it = 0; it < 3; ++it) {
    const int pix = tid + 256 * it;
    if (pix < NPX) {
      const int rr = pix / HSW;
      const int cc = pix - rr * HSW;
      const int gr = gy0 - 1 + rr;
      const int gc = gx0 - 1 + cc;
      uint32_t pk[8];
      if (((unsigned)gr < (unsigned)HH) && ((unsigned)gc < (unsigned)WW)) {
        const float* px = xb + (size_t)gr * WW + gc;
#pragma unroll
        for (int i = 0; i < 8; ++i)
          pk[i] = pack_bf16(px[(size_t)(2 * i) * HW], px[(size_t)(2 * i + 1) * HW]);
      } else {
#pragma unroll
        for (int i = 0; i < 8; ++i) pk[i] = 0u;
      }
      const int s = (cc >> 2) & 1;
      uint32_t* dst = &sx[pix * 8];
      uint4 lo, hi;
      lo.x = pk[0]; lo.y = pk[1]; lo.z = pk[2]; lo.w = pk[3];
      hi.x = pk[4]; hi.y = pk[5]; hi.z = pk[6]; hi.w = pk[7];
      *(uint4*)(dst + 4 * s)       = lo;
      *(uint4*)(dst + 4 * (1 - s)) = hi;
    }
  }
  __syncthreads();
  const int lane = tid & 63;
  const int wv   = tid >> 6;
  const int cpix = lane & 15;
  const int h4   = lane >> 4;
  const int hB   = h4 & 1;
  const int pp   = lane >> 5;
  bfx8 aw[5];
  const char* swb = (const char*)sw;
#pragma unroll
  for (int q = 0; q < 5; ++q)
    aw[q] = *(const bfx8*)(swb + cpix * 320 + q * 64 + h4 * 16);
  int Lq[5];
#pragma unroll
  for (int q = 0; q < 5; ++q) {
    int p = 2 * q + pp;
    if (p > 8) p = 8;
    const int dy = p / 3, dx = p - 3 * dy;
    const int ccl = cpix + dx;
    const int swz = (ccl >> 2) & 1;
    Lq[q] = (dy * HSW + ccl) * 32 + 16 * (hB ^ swz);
  }
  const char* sxb = (const char*)sx;
  float* yb = y + ((size_t)b * CO + h4 * 4) * HW + (size_t)gy0 * WW + gx0 + cpix;
#pragma unroll 2
  for (int ri = 0; ri < 4; ++ri) {
    const int r = wv * 4 + ri;
    const int gbase = (r * HSW) * 32;
    f32x4 a0 = {0.f, 0.f, 0.f, 0.f};
    f32x4 a1 = {0.f, 0.f, 0.f, 0.f};
#pragma unroll
    for (int q = 0; q < 5; ++q) {
      const bfx8 b0 = *(const bfx8*)(sxb + gbase + Lq[q]);
      const bfx8 b1 = *(const bfx8*)(sxb + gbase + 512 + Lq[q]);
      a0 = __builtin_amdgcn_mfma_f32_16x16x32_bf16(aw[q], b0, a0, 0, 0, 0);
      a1 = __builtin_amdgcn_mfma_f32_16x16x32_bf16(aw[q], b1, a1, 0, 0, 0);
    }
    float* yr = yb + (size_t)r * WW;
#pragma unroll
    for (int j = 0; j < 4; ++j) {
      yr[(size_t)j * HW]      = a0[j];
      yr[(size_t)j * HW + 16] = a1[j];
    }
  }
}

// ---------------------------------------------------------------------------
extern "C" void kernel_launch(void* const* d_in, const int* in_sizes, int n_in,
                              void* d_out, int out_size, void* d_ws,
                              size_t ws_size, hipStream_t stream) {
  const float* x  = (const float*)d_in[0];
  const float* Wt = (const float*)d_in[1];
  float* y = (float*)d_out;
  char* wsb = (char*)d_ws;

  const size_t need = 65536 + (size_t)BB * PW * PW * 32;  // ~76.3 MB
  if (ws_size >= need) {
    int*   pooled = (int*)wsb;               // 2304 ints
    float* att    = (float*)(wsb + 16384);   // 2304 floats
    uint4* XP     = (uint4*)(wsb + 65536);
    hipMemsetAsync(pooled, 0, BB * CI * 9 * sizeof(int), stream);
    border_kernel<<<dim3(BB), dim3(384), 0, stream>>>(XP);
    prep_kernel<<<dim3(HH / 2, BB), dim3(384), 0, stream>>>(x, XP, pooled);
    att_finish_int<<<dim3(1), dim3(256), 0, stream>>>(pooled, att);
    conv_fast<<<dim3(WW / TSW, HH / TSH, BB), dim3(256), 0, stream>>>(
        (const char*)XP, Wt, att, y);
  } else {
    float* pooled = (float*)wsb;             // 2304 floats
    float* att    = (float*)wsb + 4096;      // 2304 floats
    pool_kernel<<<dim3(BB * CI * 9), dim3(256), 0, stream>>>(x, pooled);
    att_finish<<<dim3(1), dim3(256), 0, stream>>>(pooled, att);
    conv_legacy<<<dim3(WW / TSW, HH / TSH, BB), dim3(256), 0, stream>>>(
        x, Wt, att, y);
  }
}

// Round 11
// 132.767 us; speedup vs baseline: 2.3308x; 2.3308x over previous
//
#include <hip/hip_runtime.h>
#include <hip/hip_bf16.h>
#include <math.h>

// Problem constants
#define BB   16
#define CI   16
#define CO   16
#define HH   384
#define WW   384
#define HW   (HH * WW)

// Padded pixel-major bf16 layout: XP[b][386][386][16ci], 32B per pixel
#define PW 386

// Conv tiling: 32 wide x 16 tall output tile
#define TSW 32
#define TSH 16
#define HSW 34
#define HSH 18
#define NPX (HSW * HSH)  // 612 staged pixels, 1224 16B-chunks

typedef __bf16 bfx8 __attribute__((ext_vector_type(8)));
typedef float  f32x4 __attribute__((ext_vector_type(4)));

// RNE pack of two f32 -> bf16x2 in a uint32 (lo = a, hi = b)
__device__ __forceinline__ uint32_t pack_bf16(float a, float b) {
  uint32_t ua = __builtin_bit_cast(uint32_t, a);
  uint32_t ub = __builtin_bit_cast(uint32_t, b);
  ua = (ua + 0x7FFFu + ((ua >> 16) & 1u)) >> 16;
  ub = (ub + 0x7FFFu + ((ub >> 16) & 1u)) >> 16;
  return ua | (ub << 16);
}

__device__ __forceinline__ void gl_lds16(const void* g, void* l) {
  __builtin_amdgcn_global_load_lds(
      (const __attribute__((address_space(1))) uint32_t*)g,
      (__attribute__((address_space(3))) uint32_t*)l, 16, 0, 0);
}

// ===========================================================================
// FAST PATH
// ===========================================================================

// ---------------------------------------------------------------------------
// prep: x [B][CI][H][W] f32 -> XP padded [B][386][386][CI] bf16 + pool counts.
// Grid (4, 96, B), 1024 threads. tile 0..2: data; tile 3: border zeroing.
// Thread: r = t>>8 (row in 4-row group), g = (t>>5)&7 (ci pair), c4 = t&31.
// 2 independent float4 loads -> pack -> 4 scattered u32 stores (TCC merges
// the 4B sectors; XP stays L2/L3-resident). No staging LDS, no pre-load
// barriers, ~full occupancy -> deep MLP. Pool counts: shfl within 32-lane
// group + block LDS reduce -> 16 atomics/block.
// ---------------------------------------------------------------------------
__global__ __launch_bounds__(1024) void prep_kernel(
    const float* __restrict__ x, uint32_t* __restrict__ XPu,
    int* __restrict__ pooled) {
  const int tile = blockIdx.x;   // 0..2 data col-tile, 3 = border
  const int rgrp = blockIdx.y;   // 4-row group 0..95
  const int b    = blockIdx.z;
  const int tid  = threadIdx.x;

  if (tile == 3) {  // border frame: 1540 records of 32B, spread over rgrp
    const int j = rgrp * 17 + tid;  // 96*17 = 1632 >= 1540
    if (tid < 17 && j < 1540) {
      int pr, pc;
      if (j < 386)       { pr = 0;            pc = j; }
      else if (j < 772)  { pr = PW - 1;       pc = j - 386; }
      else if (j < 1156) { pr = j - 772 + 1;  pc = 0; }
      else               { pr = j - 1156 + 1; pc = PW - 1; }
      uint4* p = (uint4*)(XPu + (((size_t)b * PW + pr) * PW + pc) * 8);
      const uint4 z = {0u, 0u, 0u, 0u};
      p[0] = z; p[1] = z;
    }
    return;
  }

  const int r  = tid >> 8;        // 0..3
  const int g  = (tid >> 5) & 7;  // ci pair index
  const int c4 = tid & 31;        // float4 col within 128-px tile
  const int h  = rgrp * 4 + r;
  const int w0 = tile * 128;

  const float* p0 =
      x + ((size_t)(b * CI + 2 * g)) * HW + (size_t)h * WW + w0 + 4 * c4;
  const f32x4 vlo = *(const f32x4*)p0;          // ci = 2g
  const f32x4 vhi = *(const f32x4*)(p0 + HW);   // ci = 2g+1

  // pack + 4 scattered u32 stores (byte offset g*4 within each 32B record)
  const size_t rec0 = ((size_t)b * PW + (h + 1)) * PW + (w0 + 4 * c4 + 1);
#pragma unroll
  for (int p = 0; p < 4; ++p)
    XPu[(rec0 + p) * 8 + g] = pack_bf16(vlo[p], vhi[p]);

  // pool counts: this thread's 2 channels over 4 px
  int clo = (vlo[0] >= 0.f) + (vlo[1] >= 0.f) + (vlo[2] >= 0.f) + (vlo[3] >= 0.f);
  int chi = (vhi[0] >= 0.f) + (vhi[1] >= 0.f) + (vhi[2] >= 0.f) + (vhi[3] >= 0.f);
#pragma unroll
  for (int s = 1; s < 32; s <<= 1) {
    clo += __shfl_xor(clo, s, 64);
    chi += __shfl_xor(chi, s, 64);
  }

  __shared__ int2 sgrp[32];  // [r*8+g]
  if ((tid & 31) == 0) sgrp[tid >> 5] = make_int2(clo, chi);
  __syncthreads();

  if (tid < CI) {
    const int ci = tid;
    const int gg = ci >> 1;
    int s = 0;
#pragma unroll
    for (int rr = 0; rr < 4; ++rr) {
      const int2 v = sgrp[rr * 8 + gg];
      s += (ci & 1) ? v.y : v.x;
    }
    const int bin = (rgrp >> 5) * 3 + tile;  // (h>>7)*3 + tile
    atomicAdd(&pooled[(b * CI + ci) * 9 + bin], s);
  }
}

// ---------------------------------------------------------------------------
// att_finish_int: softmax+sigmoid. 1 block x 256 threads (1 per plane).
// ---------------------------------------------------------------------------
__global__ __launch_bounds__(256) void att_finish_int(
    const int* __restrict__ pooled, float* __restrict__ att) {
  const int plane = threadIdx.x;
  float v[9];
#pragma unroll
  for (int k = 0; k < 9; ++k)
    v[k] = (float)pooled[plane * 9 + k] * (1.f / 16384.f);
  float m = v[0];
#pragma unroll
  for (int k = 1; k < 9; ++k) m = fmaxf(m, v[k]);
  float e[9], s = 0.f;
#pragma unroll
  for (int k = 0; k < 9; ++k) { e[k] = expf(v[k] - m); s += e[k]; }
  const float inv = 1.f / s;
#pragma unroll
  for (int k = 0; k < 9; ++k) {
    const float a = 9.f * e[k] * inv - 1.f;
    att[plane * 9 + k] = 1.f + 1.f / (1.f + expf(-a));
  }
}

// ---------------------------------------------------------------------------
// conv_fast: bf16 MFMA implicit-GEMM conv, staging from XP via global_load_lds.
// y stores are nontemporal: y is never re-read during timing, keep L3 for x+XP.
// ---------------------------------------------------------------------------
__global__ __launch_bounds__(256) void conv_fast(
    const char* __restrict__ XPc, const float* __restrict__ Wt,
    const float* __restrict__ att, float* __restrict__ y) {
  const int b   = blockIdx.z;
  const int gx0 = blockIdx.x * TSW;
  const int gy0 = blockIdx.y * TSH;
  const int tid = threadIdx.x;

  __shared__ __align__(16) uint32_t sx[NPX * 8];   // 19,584 B
  __shared__ __align__(16) uint32_t sw[CO * 80];   //  5,120 B

  const int lane = tid & 63;
  const int wv   = tid >> 6;

  // --- stage x tile from XP: 1224 16B chunks, 20 wave-iterations total ---
  const char* XPb = XPc + (size_t)b * (PW * PW * 32);
#pragma unroll
  for (int i = wv; i < 20; i += 4) {
    const int chunk = i * 64 + lane;
    const int px  = chunk >> 1;
    const int hf  = chunk & 1;
    const int rr  = px / HSW;
    const int cc  = px - rr * HSW;
    const int swz = (cc >> 2) & 1;
    const char* src =
        XPb + (((size_t)(gy0 + rr) * PW + (gx0 + cc)) << 5) + ((hf ^ swz) << 4);
    if (chunk < 2 * NPX) gl_lds16(src, (char*)sx + i * 1024);
  }

  // --- modulated weights -> sw[cout][k/2] packed bf16 pairs, k = pos*16+ci ---
#pragma unroll
  for (int i = 0; i < 5; ++i) {
    const int idx  = tid + 256 * i;  // 0..1279
    const int cout = idx / 80;
    const int kp   = idx - cout * 80;
    const int k0 = 2 * kp, k1 = 2 * kp + 1;
    const int p0 = k0 >> 4, ci0 = k0 & 15;
    const int p1 = k1 >> 4, ci1 = k1 & 15;
    float v0 = 0.f, v1 = 0.f;
    if (p0 < 9) v0 = Wt[(cout * CI + ci0) * 9 + p0] * att[(b * CI + ci0) * 9 + p0];
    if (p1 < 9) v1 = Wt[(cout * CI + ci1) * 9 + p1] * att[(b * CI + ci1) * 9 + p1];
    sw[cout * 80 + kp] = pack_bf16(v0, v1);
  }
  __syncthreads();

  const int cpix = lane & 15;        // pixel col within group / A row (cout)
  const int h4   = lane >> 4;        // 0..3: A k-group; D row group
  const int hB   = h4 & 1;           // B ci-half
  const int pp   = lane >> 5;        // B pos parity

  // A fragments: Wmod[cout=cpix][k chunk q]
  bfx8 aw[5];
  const char* swb = (const char*)sw;
#pragma unroll
  for (int q = 0; q < 5; ++q)
    aw[q] = *(const bfx8*)(swb + cpix * 320 + q * 64 + h4 * 16);

  // B per-lane byte offsets into sx for each K-chunk
  int Lq[5];
#pragma unroll
  for (int q = 0; q < 5; ++q) {
    int p = 2 * q + pp;
    if (p > 8) p = 8;                // k>=144: weights are zero; clamp addr
    const int dy = p / 3, dx = p - 3 * dy;
    const int ccl = cpix + dx;
    const int swz = (ccl >> 2) & 1;
    Lq[q] = (dy * HSW + ccl) * 32 + 16 * (hB ^ swz);
  }

  const char* sxb = (const char*)sx;
  float* yb = y + ((size_t)b * CO + h4 * 4) * HW + (size_t)gy0 * WW + gx0 + cpix;

#pragma unroll 2
  for (int ri = 0; ri < 4; ++ri) {
    const int r = wv * 4 + ri;
    const int gbase = (r * HSW) * 32;
    f32x4 a0 = {0.f, 0.f, 0.f, 0.f};
    f32x4 a1 = {0.f, 0.f, 0.f, 0.f};
#pragma unroll
    for (int q = 0; q < 5; ++q) {
      const bfx8 b0 = *(const bfx8*)(sxb + gbase + Lq[q]);
      const bfx8 b1 = *(const bfx8*)(sxb + gbase + 512 + Lq[q]);  // c0 = 16
      a0 = __builtin_amdgcn_mfma_f32_16x16x32_bf16(aw[q], b0, a0, 0, 0, 0);
      a1 = __builtin_amdgcn_mfma_f32_16x16x32_bf16(aw[q], b1, a1, 0, 0, 0);
    }
    float* yr = yb + (size_t)r * WW;
#pragma unroll
    for (int j = 0; j < 4; ++j) {
      __builtin_nontemporal_store(a0[j], &yr[(size_t)j * HW]);
      __builtin_nontemporal_store(a1[j], &yr[(size_t)j * HW + 16]);
    }
  }
}

// ===========================================================================
// LEGACY FALLBACK (round-5 path) — used only if ws_size is too small
// ===========================================================================
__global__ __launch_bounds__(256) void pool_kernel(
    const float* __restrict__ x, float* __restrict__ pooled) {
  const int bx = blockIdx.x;
  const int plane = bx / 9;
  const int bin = bx - plane * 9;
  const int br = (bin / 3) * 128;
  const int bc4 = (bin % 3) * 32;
  const float4* xp = (const float4*)(x + (size_t)plane * HW);
  const int tid = threadIdx.x;
  int cnt = 0;
#pragma unroll
  for (int k = 0; k < 16; ++k) {
    const int idx = tid + k * 256;
    const int r = idx >> 5;
    const int c4 = idx & 31;
    const float4 v = xp[(size_t)(br + r) * (WW / 4) + bc4 + c4];
    cnt += (v.x >= 0.f) + (v.y >= 0.f) + (v.z >= 0.f) + (v.w >= 0.f);
  }
#pragma unroll
  for (int s = 32; s > 0; s >>= 1) cnt += __shfl_down(cnt, s);
  __shared__ int wsum[4];
  const int lane = tid & 63, wid = tid >> 6;
  if (lane == 0) wsum[wid] = cnt;
  __syncthreads();
  if (tid == 0)
    pooled[bx] = (float)(wsum[0] + wsum[1] + wsum[2] + wsum[3]) * (1.f / 16384.f);
}

__global__ __launch_bounds__(256) void att_finish(
    const float* __restrict__ pooled, float* __restrict__ att) {
  const int plane = threadIdx.x;
  float v[9];
#pragma unroll
  for (int k = 0; k < 9; ++k) v[k] = pooled[plane * 9 + k];
  float m = v[0];
#pragma unroll
  for (int k = 1; k < 9; ++k) m = fmaxf(m, v[k]);
  float e[9], s = 0.f;
#pragma unroll
  for (int k = 0; k < 9; ++k) { e[k] = expf(v[k] - m); s += e[k]; }
  const float inv = 1.f / s;
#pragma unroll
  for (int k = 0; k < 9; ++k) {
    const float a = 9.f * e[k] * inv - 1.f;
    att[plane * 9 + k] = 1.f + 1.f / (1.f + expf(-a));
  }
}

__global__ __launch_bounds__(256) void conv_legacy(
    const float* __restrict__ x, const float* __restrict__ Wt,
    const float* __restrict__ att, float* __restrict__ y) {
  const int b   = blockIdx.z;
  const int gx0 = blockIdx.x * TSW;
  const int gy0 = blockIdx.y * TSH;
  const int tid = threadIdx.x;
  __shared__ __align__(16) uint32_t sx[NPX * 8];
  __shared__ __align__(16) uint32_t sw[CO * 80];
  const float* xb = x + (size_t)b * CI * HW;
#pragma unroll
  for (int i = 0; i < 5; ++i) {
    const int idx  = tid + 256 * i;
    const int cout = idx / 80;
    const int kp   = idx - cout * 80;
    const int k0 = 2 * kp, k1 = 2 * kp + 1;
    const int p0 = k0 >> 4, ci0 = k0 & 15;
    const int p1 = k1 >> 4, ci1 = k1 & 15;
    float v0 = 0.f, v1 = 0.f;
    if (p0 < 9) v0 = Wt[(cout * CI + ci0) * 9 + p0] * att[(b * CI + ci0) * 9 + p0];
    if (p1 < 9) v1 = Wt[(cout * CI + ci1) * 9 + p1] * att[(b * CI + ci1) * 9 + p1];
    sw[cout * 80 + kp] = pack_bf16(v0, v1);
  }
#pragma unroll
  for (int it = 0; it < 3; ++it) {
    const int pix = tid + 256 * it;
    if (pix < NPX) {
      const int rr = pix / HSW;
      const int cc = pix - rr * HSW;
      const int gr = gy0 - 1 + rr;
      const int gc = gx0 - 1 + cc;
      uint32_t pk[8];
      if (((unsigned)gr < (unsigned)HH) && ((unsigned)gc < (unsigned)WW)) {
        const float* px = xb + (size_t)gr * WW + gc;
#pragma unroll
        for (int i = 0; i < 8; ++i)
          pk[i] = pack_bf16(px[(size_t)(2 * i) * HW], px[(size_t)(2 * i + 1) * HW]);
      } else {
#pragma unroll
        for (int i = 0; i < 8; ++i) pk[i] = 0u;
      }
      const int s = (cc >> 2) & 1;
      uint32_t* dst = &sx[pix * 8];
      uint4 lo, hi;
      lo.x = pk[0]; lo.y = pk[1]; lo.z = pk[2]; lo.w = pk[3];
      hi.x = pk[4]; hi.y = pk[5]; hi.z = pk[6]; hi.w = pk[7];
      *(uint4*)(dst + 4 * s)       = lo;
      *(uint4*)(dst + 4 * (1 - s)) = hi;
    }
  }
  __syncthreads();
  const int lane = tid & 63;
  const int wv   = tid >> 6;
  const int cpix = lane & 15;
  const int h4   = lane >> 4;
  const int hB   = h4 & 1;
  const int pp   = lane >> 5;
  bfx8 aw[5];
  const char* swb = (const char*)sw;
#pragma unroll
  for (int q = 0; q < 5; ++q)
    aw[q] = *(const bfx8*)(swb + cpix * 320 + q * 64 + h4 * 16);
  int Lq[5];
#pragma unroll
  for (int q = 0; q < 5; ++q) {
    int p = 2 * q + pp;
    if (p > 8) p = 8;
    const int dy = p / 3, dx = p - 3 * dy;
    const int ccl = cpix + dx;
    const int swz = (ccl >> 2) & 1;
    Lq[q] = (dy * HSW + ccl) * 32 + 16 * (hB ^ swz);
  }
  const char* sxb = (const char*)sx;
  float* yb = y + ((size_t)b * CO + h4 * 4) * HW + (size_t)gy0 * WW + gx0 + cpix;
#pragma unroll 2
  for (int ri = 0; ri < 4; ++ri) {
    const int r = wv * 4 + ri;
    const int gbase = (r * HSW) * 32;
    f32x4 a0 = {0.f, 0.f, 0.f, 0.f};
    f32x4 a1 = {0.f, 0.f, 0.f, 0.f};
#pragma unroll
    for (int q = 0; q < 5; ++q) {
      const bfx8 b0 = *(const bfx8*)(sxb + gbase + Lq[q]);
      const bfx8 b1 = *(const bfx8*)(sxb + gbase + 512 + Lq[q]);
      a0 = __builtin_amdgcn_mfma_f32_16x16x32_bf16(aw[q], b0, a0, 0, 0, 0);
      a1 = __builtin_amdgcn_mfma_f32_16x16x32_bf16(aw[q], b1, a1, 0, 0, 0);
    }
    float* yr = yb + (size_t)r * WW;
#pragma unroll
    for (int j = 0; j < 4; ++j) {
      yr[(size_t)j * HW]      = a0[j];
      yr[(size_t)j * HW + 16] = a1[j];
    }
  }
}

// ---------------------------------------------------------------------------
extern "C" void kernel_launch(void* const* d_in, const int* in_sizes, int n_in,
                              void* d_out, int out_size, void* d_ws,
                              size_t ws_size, hipStream_t stream) {
  const float* x  = (const float*)d_in[0];
  const float* Wt = (const float*)d_in[1];
  float* y = (float*)d_out;
  char* wsb = (char*)d_ws;

  const size_t need = 65536 + (size_t)BB * PW * PW * 32;  // ~76.3 MB
  if (ws_size >= need) {
    int*      pooled = (int*)wsb;               // 2304 ints
    float*    att    = (float*)(wsb + 16384);   // 2304 floats
    uint32_t* XPu    = (uint32_t*)(wsb + 65536);
    hipMemsetAsync(pooled, 0, BB * CI * 9 * sizeof(int), stream);
    prep_kernel<<<dim3(4, 96, BB), dim3(1024), 0, stream>>>(x, XPu, pooled);
    att_finish_int<<<dim3(1), dim3(256), 0, stream>>>(pooled, att);
    conv_fast<<<dim3(WW / TSW, HH / TSH, BB), dim3(256), 0, stream>>>(
        (const char*)XPu, Wt, att, y);
  } else {
    float* pooled = (float*)wsb;             // 2304 floats
    float* att    = (float*)wsb + 4096;      // 2304 floats
    pool_kernel<<<dim3(BB * CI * 9), dim3(256), 0, stream>>>(x, pooled);
    att_finish<<<dim3(1), dim3(256), 0, stream>>>(pooled, att);
    conv_legacy<<<dim3(WW / TSW, HH / TSH, BB), dim3(256), 0, stream>>>(
        x, Wt, att, y);
  }
}